// Round 1
// baseline (269.534 us; speedup 1.0000x reference)
//
#include <hip/hip_runtime.h>
#include <stdint.h>

// Problem constants
#define CCH   64
#define HWSZ  3136        // 56*56
#define NB    128
#define MCOLS 401408      // NB*HWSZ
#define TK    128         // K1 tile columns
#define NTILES 3136       // MCOLS / TK
#define LDK   136         // TK+8 bf16 stride (272 B, 16B-aligned, conflict-benign)
#define LDB   72          // K2 bf16 row stride (144 B, 16B-aligned)
#define SLOT  4160        // per-block partial: 4096 gram + 64 sums (floats)
#define WS_TAIL 16512     // gram|sums|wm|bvec|Ag|wmh|wml floats at ws[0..)
#define RG    32          // reduction tree fan-in groups
#define K1MAX 1024        // k1 grid cap: 4 blocks/CU, 3-4 tiles/block
#define LDT   72          // K3 xT row stride in shorts (144 B, 16B-aligned)

typedef short bf16x8 __attribute__((ext_vector_type(8)));
typedef float f32x4  __attribute__((ext_vector_type(4)));
typedef unsigned short u16x4 __attribute__((ext_vector_type(4)));

__device__ __forceinline__ unsigned short f2bf(float f) {
    union { float f; uint32_t u; } v; v.f = f;
    uint32_t r = v.u + 0x7fffu + ((v.u >> 16) & 1u);   // round-to-nearest-even
    return (unsigned short)(r >> 16);
}
__device__ __forceinline__ float bf2f(unsigned short h) {
    union { uint32_t u; float f; } v; v.u = ((uint32_t)h) << 16; return v.f;
}

// ---------------------------------------------------------------------------
// K1: per-channel sums + gram = X*X^T via bf16 MFMA (gram symmetric => immune
// to C/D transpose). Grid-stride over tiles, private per-block partials (no
// atomics — R1: 6.4M RMWs on 16KB serialized to 700us). Register-prefetch
// pipeline (next tile's loads issued before the MFMA section).
// ---------------------------------------------------------------------------
__global__ __launch_bounds__(256) void k1_gram(const float* __restrict__ X,
                                               float* __restrict__ part,
                                               int nb) {
    __shared__ __align__(16) unsigned short tile[CCH * LDK];  // 17408 B
    const int tid = threadIdx.x;
    const int w = tid >> 6, l = tid & 63;

    f32x4 acc[4];
    #pragma unroll
    for (int b = 0; b < 4; ++b) acc[b] = (f32x4){0.f, 0.f, 0.f, 0.f};
    float sacc[16];
    #pragma unroll
    for (int i = 0; i < 16; ++i) sacc[i] = 0.f;

    float2 xv[16];

    // prologue: load first tile into registers
    uint32_t t = blockIdx.x;
    {
        const uint32_t s = t * TK + 2u * (uint32_t)l;  // even => float2 never crosses n
        const uint32_t n = s / HWSZ;
        const uint32_t hw = s - n * HWSZ;
        const size_t base = (size_t)n * (CCH * HWSZ) + hw + (size_t)w * HWSZ;
        #pragma unroll
        for (int i = 0; i < 16; ++i)
            xv[i] = *(const float2*)(X + base + (size_t)i * (4u * HWSZ));
    }

    for (;;) {
        __syncthreads();  // previous tile's LDS readers done
        // stage registers -> LDS (channel c = 4*i + w)
        #pragma unroll
        for (int i = 0; i < 16; ++i) {
            sacc[i] += xv[i].x + xv[i].y;
            const int c = 4 * i + w;
            *(uint32_t*)&tile[c * LDK + 2 * l] =
                (uint32_t)f2bf(xv[i].x) | ((uint32_t)f2bf(xv[i].y) << 16);
        }
        __syncthreads();

        // prefetch next tile (loads overlap the MFMA section below)
        const uint32_t tn = t + (uint32_t)nb;
        const bool more = tn < NTILES;
        if (more) {
            const uint32_t s = tn * TK + 2u * (uint32_t)l;
            const uint32_t n = s / HWSZ;
            const uint32_t hw = s - n * HWSZ;
            const size_t base = (size_t)n * (CCH * HWSZ) + hw + (size_t)w * HWSZ;
            #pragma unroll
            for (int i = 0; i < 16; ++i)
                xv[i] = *(const float2*)(X + base + (size_t)i * (4u * HWSZ));
        }

        // MFMA: wave w computes gram row-block w x col-blocks 0..3
        #pragma unroll
        for (int k0 = 0; k0 < TK; k0 += 32) {
            const int koff = k0 + ((l >> 4) << 3);
            const bf16x8 fa = *(const bf16x8*)&tile[(16 * w + (l & 15)) * LDK + koff];
            #pragma unroll
            for (int bj = 0; bj < 4; ++bj) {
                const bf16x8 fb = *(const bf16x8*)&tile[(16 * bj + (l & 15)) * LDK + koff];
                acc[bj] = __builtin_amdgcn_mfma_f32_16x16x32_bf16(fa, fb, acc[bj], 0, 0, 0);
            }
        }

        if (!more) break;
        t = tn;
    }

    // epilogue: plain stores to this block's private slot
    float* pg = part + (size_t)blockIdx.x * SLOT;
    #pragma unroll
    for (int bj = 0; bj < 4; ++bj) {
        #pragma unroll
        for (int r = 0; r < 4; ++r) {
            const int row = 16 * w + ((l >> 4) << 2) + r;
            const int col = 16 * bj + (l & 15);
            pg[row * 64 + col] = acc[bj][r];
        }
    }
    #pragma unroll
    for (int i = 0; i < 16; ++i) {
        float v = sacc[i];
        #pragma unroll
        for (int m = 32; m > 0; m >>= 1) v += __shfl_xor(v, m, 64);
        if (l == 0) pg[4096 + 4 * i + w] = v;
    }
}

// ---------------------------------------------------------------------------
// K1b stage 1: 17*RG blocks. Block (g = bx/17) sums slots {g, g+RG, ...} into
// part2[g]. 4 independent accumulators break the R2 dependent-load chain
// (R2: 17 blocks x 448 serial loads = 107us latency-bound).
// ---------------------------------------------------------------------------
__global__ __launch_bounds__(256) void k1b1_reduce(const float* __restrict__ part,
                                                   float* __restrict__ part2,
                                                   int nb) {
    const int bx = blockIdx.x;
    const int g = bx / 17;
    const int e = (bx - g * 17) * 256 + threadIdx.x;
    if (e >= SLOT) return;
    float a0 = 0.f, a1 = 0.f, a2 = 0.f, a3 = 0.f;
    int b = g;
    for (; b + 3 * RG < nb; b += 4 * RG) {
        a0 += part[(size_t)b * SLOT + e];
        a1 += part[(size_t)(b + RG) * SLOT + e];
        a2 += part[(size_t)(b + 2 * RG) * SLOT + e];
        a3 += part[(size_t)(b + 3 * RG) * SLOT + e];
    }
    for (; b < nb; b += RG) a0 += part[(size_t)b * SLOT + e];
    part2[(size_t)g * SLOT + e] = (a0 + a1) + (a2 + a3);
}

// K1b stage 2: fold RG group-partials -> ws[0..4159] (gram 4096 | sums 64)
__global__ __launch_bounds__(256) void k1b2_reduce(const float* __restrict__ part2,
                                                   float* __restrict__ out) {
    const int e = blockIdx.x * 256 + threadIdx.x;
    if (e >= SLOT) return;
    float a0 = 0.f, a1 = 0.f, a2 = 0.f, a3 = 0.f;
    #pragma unroll
    for (int b = 0; b < RG; b += 4) {
        a0 += part2[(size_t)b * SLOT + e];
        a1 += part2[(size_t)(b + 1) * SLOT + e];
        a2 += part2[(size_t)(b + 2) * SLOT + e];
        a3 += part2[(size_t)(b + 3) * SLOT + e];
    }
    out[e] = (a0 + a1) + (a2 + a3);
}

// ---------------------------------------------------------------------------
// K2 helpers: 64x64 matmuls on one workgroup via MFMA. All operands are
// symmetric (polynomials in A), so B-frags read R's rows directly.
// ---------------------------------------------------------------------------
__device__ __forceinline__ bf16x8 ldfrag_h(const unsigned short* H, int rowbase, int k0, int l) {
    const int row = rowbase + (l & 15);
    const int koff = k0 + ((l >> 4) << 3);
    return *(const bf16x8*)&H[row * LDB + koff];
}
__device__ __forceinline__ bf16x8 ldfrag_lo(const float* F, bf16x8 hi, int rowbase, int k0, int l) {
    const int row = rowbase + (l & 15);
    const int koff = k0 + ((l >> 4) << 3);
    const float* p = F + row * 64 + koff;
    bf16x8 lo;
    #pragma unroll
    for (int j = 0; j < 8; ++j)
        lo[j] = (short)f2bf(p[j] - bf2f((unsigned short)hi[j]));
    return lo;
}

__device__ void mm_plain(const unsigned short* Lh, const unsigned short* Rh,
                         unsigned short* DH, float* DF, int tid) {
    const int w = tid >> 6, l = tid & 63;
    f32x4 acc[4];
    #pragma unroll
    for (int b = 0; b < 4; ++b) acc[b] = (f32x4){0.f, 0.f, 0.f, 0.f};
    #pragma unroll
    for (int k0 = 0; k0 < 64; k0 += 32) {
        const bf16x8 la = ldfrag_h(Lh, 16 * w, k0, l);
        #pragma unroll
        for (int b = 0; b < 4; ++b) {
            const bf16x8 rb = ldfrag_h(Rh, 16 * b, k0, l);
            acc[b] = __builtin_amdgcn_mfma_f32_16x16x32_bf16(la, rb, acc[b], 0, 0, 0);
        }
    }
    __syncthreads();  // allow in-place D==R
    #pragma unroll
    for (int b = 0; b < 4; ++b) {
        #pragma unroll
        for (int r = 0; r < 4; ++r) {
            const int row = 16 * w + ((l >> 4) << 2) + r;
            const int col = 16 * b + (l & 15);
            const float v = acc[b][r];
            if (DH) DH[row * LDB + col] = f2bf(v);
            if (DF) DF[row * 64 + col] = v;
        }
    }
    __syncthreads();
}

__device__ void mm_split(const unsigned short* Lh, const float* Lf,
                         const unsigned short* Rh, const float* Rf,
                         unsigned short* DH, float* DF, int tid) {
    const int w = tid >> 6, l = tid & 63;
    f32x4 acc[4];
    #pragma unroll
    for (int b = 0; b < 4; ++b) acc[b] = (f32x4){0.f, 0.f, 0.f, 0.f};
    #pragma unroll
    for (int k0 = 0; k0 < 64; k0 += 32) {
        const bf16x8 lah = ldfrag_h(Lh, 16 * w, k0, l);
        const bf16x8 lal = ldfrag_lo(Lf, lah, 16 * w, k0, l);
        #pragma unroll
        for (int b = 0; b < 4; ++b) {
            const bf16x8 rbh = ldfrag_h(Rh, 16 * b, k0, l);
            const bf16x8 rbl = ldfrag_lo(Rf, rbh, 16 * b, k0, l);
            acc[b] = __builtin_amdgcn_mfma_f32_16x16x32_bf16(lah, rbh, acc[b], 0, 0, 0);
            acc[b] = __builtin_amdgcn_mfma_f32_16x16x32_bf16(lah, rbl, acc[b], 0, 0, 0);
            acc[b] = __builtin_amdgcn_mfma_f32_16x16x32_bf16(lal, rbh, acc[b], 0, 0, 0);
        }
    }
    __syncthreads();  // allow in-place D==R
    #pragma unroll
    for (int b = 0; b < 4; ++b) {
        #pragma unroll
        for (int r = 0; r < 4; ++r) {
            const int row = 16 * w + ((l >> 4) << 2) + r;
            const int col = 16 * b + (l & 15);
            const float v = acc[b][r];
            if (DH) DH[row * LDB + col] = f2bf(v);
            if (DF) DF[row * 64 + col] = v;
        }
    }
    __syncthreads();
}

// ---------------------------------------------------------------------------
// K2: sigma -> Newton-Schulz inverse sqrt -> wm (as bf16 hi/lo pair), b.
// Single workgroup.
// ---------------------------------------------------------------------------
__global__ __launch_bounds__(256) void k2_ns(float* __restrict__ ws) {
    const float* gram = ws;
    const float* sums = ws + 4096;
    float* bvec = ws + 8256;
    float* Ag = ws + 8320;  // fp32 A = sigma/s (global, for polish lo-frags)
    unsigned short* wmh = (unsigned short*)(ws + 12416);  // bf16 hi of wm [64][64]
    unsigned short* wml = (unsigned short*)(ws + 14464);  // bf16 lo of wm [64][64]

    __shared__ float Zf[4096];
    __shared__ float Sf[4096];
    __shared__ __align__(16) unsigned short Ah[64 * LDB];
    __shared__ __align__(16) unsigned short ZhA[64 * LDB];
    __shared__ __align__(16) unsigned short Bh[64 * LDB];
    __shared__ float mu[64];
    __shared__ float sred[1];

    const int tid = threadIdx.x;
    const float invm = 1.0f / (float)MCOLS;

    if (tid < 64) mu[tid] = sums[tid] * invm;
    __syncthreads();

    // sigma -> Sf
    #pragma unroll
    for (int j = 0; j < 16; ++j) {
        const int e = tid * 16 + j;
        const int i = e >> 6, c = e & 63;
        Sf[e] = gram[e] * invm - mu[i] * mu[c] + ((i == c) ? 1e-3f : 0.0f);
    }
    __syncthreads();

    // s = ||sigma||_inf (Gershgorin bound on lambda_max)
    if (tid < 64) {
        float rs = 0.f;
        #pragma unroll
        for (int j = 0; j < 64; ++j) {
            const int c = (j + tid) & 63;  // rotate start -> conflict-free
            rs += fabsf(Sf[tid * 64 + c]);
        }
        #pragma unroll
        for (int m = 32; m > 0; m >>= 1) rs = fmaxf(rs, __shfl_xor(rs, m, 64));
        if (tid == 0) sred[0] = rs;
    }
    __syncthreads();
    const float s = sred[0];
    const float invs = 1.0f / s;

    // A = sigma/s (fp32 to Ag, bf16-hi to Ah); Z = I
    #pragma unroll
    for (int j = 0; j < 16; ++j) {
        const int e = tid * 16 + j;
        const int i = e >> 6, c = e & 63;
        const float a = Sf[e] * invs;
        Ag[e] = a;
        Ah[i * LDB + c] = f2bf(a);
        const float z = (i == c) ? 1.0f : 0.0f;
        Zf[e] = z;
        ZhA[i * LDB + c] = f2bf(z);
    }
    __syncthreads();

    // 4 plain bf16 NS iterations: Z <- 1.5 Z - 0.5 Z*(A*(Z*Z))
    for (int itn = 0; itn < 4; ++itn) {
        mm_plain(ZhA, ZhA, Bh, nullptr, tid);   // M = Z*Z
        mm_plain(Ah, Bh, Bh, nullptr, tid);     // W = A*M (in-place OK)
        mm_plain(ZhA, Bh, nullptr, Sf, tid);    // V = Z*W -> fp32
        #pragma unroll
        for (int j = 0; j < 16; ++j) {
            const int e = tid * 16 + j;
            const int i = e >> 6, c = e & 63;
            const float z = 1.5f * Zf[e] - 0.5f * Sf[e];
            Zf[e] = z;
            ZhA[i * LDB + c] = f2bf(z);
        }
        __syncthreads();
    }

    // polish: one NS step at ~fp32 precision via split-bf16 (hi*hi+hi*lo+lo*hi)
    mm_split(ZhA, Zf, ZhA, Zf, Bh, Sf, tid);     // M = Z*Z     -> (Bh, Sf)
    mm_split(Ah, Ag, Bh, Sf, Bh, Sf, tid);       // W = A*M     -> (Bh, Sf)
    mm_split(ZhA, Zf, Bh, Sf, nullptr, Sf, tid); // V = Z*W     -> Sf

    const float wsq = 1.0f / sqrtf(s);  // wm = Z / sqrt(s)
    #pragma unroll
    for (int j = 0; j < 16; ++j) {
        const int e = tid * 16 + j;
        const float z = 1.5f * Zf[e] - 0.5f * Sf[e];
        Zf[e] = z;
        const float wv = z * wsq;
        const unsigned short h = f2bf(wv);
        wmh[e] = h;
        wml[e] = f2bf(wv - bf2f(h));
    }
    __syncthreads();

    // b = wm * mu
    if (tid < 64) {
        float acc = 0.f;
        #pragma unroll
        for (int j = 0; j < 64; ++j) {
            const int c = (j + tid) & 63;
            acc += Zf[tid * 64 + c] * mu[c];
        }
        bvec[tid] = acc * wsq;
    }
}

// ---------------------------------------------------------------------------
// K3: out[n][c][hw] = sum_k wm[c][k] * X[n][k][hw] - bvec[c], via MFMA.
// R5 rewrite: R4's scalar-FMA version had a hard VALU-issue floor (~27us:
// 64 x 16 v_fmac per thread = 1.64G lane-FMAs at 78.6T/s) on top of its
// ~30us memory stream. Move the 64x64xM GEMM onto the matrix pipe with
// split-bf16 (hi*hi + hi*lo + lo*hi ~ fp32; lo*lo ~ 2^-16 dropped):
// 9.9 GFLOP of MFMA hides entirely under the 206 MB HBM/L3 stream.
// Layout: stage X tile transposed (xT[pos][ch] bf16 hi/lo, stride 72 shorts
// = 144 B, 16B-aligned, <=8-way bank aliasing only on the cheap staging
// writes). A-frags = xT rows (positions), B-frags = wm rows read straight
// from global (16 KB, L2-hot). D[p][c]: p = 16w + (l>>4)*4 + r -> contiguous
// f32x4 store per channel row; 64 | 3136 so a tile never crosses an image.
// ---------------------------------------------------------------------------
__global__ __launch_bounds__(256, 2) void k3_whiten(const float* __restrict__ X,
                                                    const float* __restrict__ ws,
                                                    float* __restrict__ out) {
    __shared__ __align__(16) unsigned short xh[64 * LDT];  // 9216 B
    __shared__ __align__(16) unsigned short xl[64 * LDT];  // 9216 B
    const int tid = threadIdx.x;
    const int w = tid >> 6, l = tid & 63;

    const unsigned short* __restrict__ wmh = (const unsigned short*)(ws + 12416);
    const unsigned short* __restrict__ wml = (const unsigned short*)(ws + 14464);
    const float* __restrict__ bvec = ws + 8256;

    const uint32_t g = blockIdx.x;           // 6272 posgroups, 49/image
    const uint32_t n = g / 49u;
    const uint32_t hw0 = (g - n * 49u) * 64u;
    const size_t base = (size_t)n * (CCH * HWSZ) + hw0;

    // stage 64ch x 64pos transposed: lane l <-> pos, wave w covers 16 channels
    #pragma unroll
    for (int u = 0; u < 4; ++u) {
        const int c0 = (w * 4 + u) * 4;
        float x0 = X[base + (size_t)(c0 + 0) * HWSZ + l];
        float x1 = X[base + (size_t)(c0 + 1) * HWSZ + l];
        float x2 = X[base + (size_t)(c0 + 2) * HWSZ + l];
        float x3 = X[base + (size_t)(c0 + 3) * HWSZ + l];
        u16x4 hv, lv;
        hv[0] = f2bf(x0); lv[0] = f2bf(x0 - bf2f(hv[0]));
        hv[1] = f2bf(x1); lv[1] = f2bf(x1 - bf2f(hv[1]));
        hv[2] = f2bf(x2); lv[2] = f2bf(x2 - bf2f(hv[2]));
        hv[3] = f2bf(x3); lv[3] = f2bf(x3 - bf2f(hv[3]));
        *(u16x4*)&xh[l * LDT + c0] = hv;
        *(u16x4*)&xl[l * LDT + c0] = lv;
    }
    __syncthreads();

    f32x4 acc[4];
    #pragma unroll
    for (int b = 0; b < 4; ++b) acc[b] = (f32x4){0.f, 0.f, 0.f, 0.f};

    const int frow = (16 * w + (l & 15)) * LDT;
    const int koffL = (l >> 4) << 3;
    #pragma unroll
    for (int k0 = 0; k0 < 64; k0 += 32) {
        const bf16x8 fah = *(const bf16x8*)&xh[frow + k0 + koffL];
        const bf16x8 fal = *(const bf16x8*)&xl[frow + k0 + koffL];
        #pragma unroll
        for (int cb = 0; cb < 4; ++cb) {
            const int c = cb * 16 + (l & 15);
            const bf16x8 fbh = *(const bf16x8*)&wmh[c * 64 + k0 + koffL];
            const bf16x8 fbl = *(const bf16x8*)&wml[c * 64 + k0 + koffL];
            acc[cb] = __builtin_amdgcn_mfma_f32_16x16x32_bf16(fah, fbh, acc[cb], 0, 0, 0);
            acc[cb] = __builtin_amdgcn_mfma_f32_16x16x32_bf16(fah, fbl, acc[cb], 0, 0, 0);
            acc[cb] = __builtin_amdgcn_mfma_f32_16x16x32_bf16(fal, fbh, acc[cb], 0, 0, 0);
        }
    }

    // D[p][c]: lane's 4 acc values are consecutive positions of one channel
    const int p0 = 16 * w + ((l >> 4) << 2);
    #pragma unroll
    for (int cb = 0; cb < 4; ++cb) {
        const int c = cb * 16 + (l & 15);
        const float bv = bvec[c];
        f32x4 v;
        v[0] = acc[cb][0] - bv;
        v[1] = acc[cb][1] - bv;
        v[2] = acc[cb][2] - bv;
        v[3] = acc[cb][3] - bv;
        *(f32x4*)&out[base + (size_t)c * HWSZ + p0] = v;
    }
}

// ---------------------------------------------------------------------------
extern "C" void kernel_launch(void* const* d_in, const int* in_sizes, int n_in,
                              void* d_out, int out_size, void* d_ws, size_t ws_size,
                              hipStream_t stream) {
    (void)in_sizes; (void)n_in; (void)out_size;
    const float* X = (const float*)d_in[0];
    float* out = (float*)d_out;
    float* ws = (float*)d_ws;

    // ws layout: [0..WS_TAIL) result area | nb K1 slots | RG stage-2 slots
    long avail = (long)(ws_size / sizeof(float)) - WS_TAIL - (long)RG * SLOT;
    int nb = (int)(avail / SLOT);
    if (nb > K1MAX) nb = K1MAX;
    if (nb < 1) nb = 1;

    float* part = ws + WS_TAIL;
    float* part2 = part + (size_t)nb * SLOT;

    k1_gram<<<nb, 256, 0, stream>>>(X, part, nb);
    k1b1_reduce<<<17 * RG, 256, 0, stream>>>(part, part2, nb);
    k1b2_reduce<<<17, 256, 0, stream>>>(part2, ws);
    k2_ns<<<1, 256, 0, stream>>>(ws);
    k3_whiten<<<MCOLS / 64, 256, 0, stream>>>(X, ws, out);
}

// Round 2
// 242.829 us; speedup vs baseline: 1.1100x; 1.1100x over previous
//
#include <hip/hip_runtime.h>
#include <stdint.h>

// Problem constants
#define CCH   64
#define HWSZ  3136        // 56*56
#define NB    128
#define MCOLS 401408      // NB*HWSZ
#define TK    128         // K1 tile columns
#define NTILES 3136       // MCOLS / TK
#define LDK   136         // TK+8 bf16 stride (272 B, 16B-aligned, conflict-benign)
#define LDB   72          // K2 bf16 row stride (144 B, 16B-aligned)
#define SLOT  4160        // per-block partial: 4096 gram + 64 sums (floats)
#define WS_TAIL 16512     // gram|sums|wm|bvec|Ag|wmh|wml floats at ws[0..)
#define RG    32          // reduction tree fan-in groups
#define K1MAX 1024        // k1 grid cap: 4 blocks/CU, 3-4 tiles/block
#define LDT   72          // K3 xT row stride in shorts (144 B, 16B-aligned)
#define K3NB  1024        // K3 grid: 4 blocks/CU, ~6 tiles/block
#define K3T   6272        // MCOLS/64 posgroups

typedef short bf16x8 __attribute__((ext_vector_type(8)));
typedef float f32x4  __attribute__((ext_vector_type(4)));
typedef unsigned short u16x4 __attribute__((ext_vector_type(4)));

__device__ __forceinline__ unsigned short f2bf(float f) {
    union { float f; uint32_t u; } v; v.f = f;
    uint32_t r = v.u + 0x7fffu + ((v.u >> 16) & 1u);   // round-to-nearest-even
    return (unsigned short)(r >> 16);
}
__device__ __forceinline__ float bf2f(unsigned short h) {
    union { uint32_t u; float f; } v; v.u = ((uint32_t)h) << 16; return v.f;
}

// ---------------------------------------------------------------------------
// K1: per-channel sums + gram = X*X^T via bf16 MFMA (gram symmetric => immune
// to C/D transpose). Grid-stride over tiles, private per-block partials (no
// atomics — R1: 6.4M RMWs on 16KB serialized to 700us). Register-prefetch
// pipeline (next tile's loads issued before the MFMA section).
// ---------------------------------------------------------------------------
__global__ __launch_bounds__(256) void k1_gram(const float* __restrict__ X,
                                               float* __restrict__ part,
                                               int nb) {
    __shared__ __align__(16) unsigned short tile[CCH * LDK];  // 17408 B
    const int tid = threadIdx.x;
    const int w = tid >> 6, l = tid & 63;

    f32x4 acc[4];
    #pragma unroll
    for (int b = 0; b < 4; ++b) acc[b] = (f32x4){0.f, 0.f, 0.f, 0.f};
    float sacc[16];
    #pragma unroll
    for (int i = 0; i < 16; ++i) sacc[i] = 0.f;

    float2 xv[16];

    // prologue: load first tile into registers
    uint32_t t = blockIdx.x;
    {
        const uint32_t s = t * TK + 2u * (uint32_t)l;  // even => float2 never crosses n
        const uint32_t n = s / HWSZ;
        const uint32_t hw = s - n * HWSZ;
        const size_t base = (size_t)n * (CCH * HWSZ) + hw + (size_t)w * HWSZ;
        #pragma unroll
        for (int i = 0; i < 16; ++i)
            xv[i] = *(const float2*)(X + base + (size_t)i * (4u * HWSZ));
    }

    for (;;) {
        __syncthreads();  // previous tile's LDS readers done
        // stage registers -> LDS (channel c = 4*i + w)
        #pragma unroll
        for (int i = 0; i < 16; ++i) {
            sacc[i] += xv[i].x + xv[i].y;
            const int c = 4 * i + w;
            *(uint32_t*)&tile[c * LDK + 2 * l] =
                (uint32_t)f2bf(xv[i].x) | ((uint32_t)f2bf(xv[i].y) << 16);
        }
        __syncthreads();

        // prefetch next tile (loads overlap the MFMA section below)
        const uint32_t tn = t + (uint32_t)nb;
        const bool more = tn < NTILES;
        if (more) {
            const uint32_t s = tn * TK + 2u * (uint32_t)l;
            const uint32_t n = s / HWSZ;
            const uint32_t hw = s - n * HWSZ;
            const size_t base = (size_t)n * (CCH * HWSZ) + hw + (size_t)w * HWSZ;
            #pragma unroll
            for (int i = 0; i < 16; ++i)
                xv[i] = *(const float2*)(X + base + (size_t)i * (4u * HWSZ));
        }

        // MFMA: wave w computes gram row-block w x col-blocks 0..3
        #pragma unroll
        for (int k0 = 0; k0 < TK; k0 += 32) {
            const int koff = k0 + ((l >> 4) << 3);
            const bf16x8 fa = *(const bf16x8*)&tile[(16 * w + (l & 15)) * LDK + koff];
            #pragma unroll
            for (int bj = 0; bj < 4; ++bj) {
                const bf16x8 fb = *(const bf16x8*)&tile[(16 * bj + (l & 15)) * LDK + koff];
                acc[bj] = __builtin_amdgcn_mfma_f32_16x16x32_bf16(fa, fb, acc[bj], 0, 0, 0);
            }
        }

        if (!more) break;
        t = tn;
    }

    // epilogue: plain stores to this block's private slot
    float* pg = part + (size_t)blockIdx.x * SLOT;
    #pragma unroll
    for (int bj = 0; bj < 4; ++bj) {
        #pragma unroll
        for (int r = 0; r < 4; ++r) {
            const int row = 16 * w + ((l >> 4) << 2) + r;
            const int col = 16 * bj + (l & 15);
            pg[row * 64 + col] = acc[bj][r];
        }
    }
    #pragma unroll
    for (int i = 0; i < 16; ++i) {
        float v = sacc[i];
        #pragma unroll
        for (int m = 32; m > 0; m >>= 1) v += __shfl_xor(v, m, 64);
        if (l == 0) pg[4096 + 4 * i + w] = v;
    }
}

// ---------------------------------------------------------------------------
// K1b stage 1: 17*RG blocks. Block (g = bx/17) sums slots {g, g+RG, ...} into
// part2[g]. 4 independent accumulators break the R2 dependent-load chain
// (R2: 17 blocks x 448 serial loads = 107us latency-bound).
// ---------------------------------------------------------------------------
__global__ __launch_bounds__(256) void k1b1_reduce(const float* __restrict__ part,
                                                   float* __restrict__ part2,
                                                   int nb) {
    const int bx = blockIdx.x;
    const int g = bx / 17;
    const int e = (bx - g * 17) * 256 + threadIdx.x;
    if (e >= SLOT) return;
    float a0 = 0.f, a1 = 0.f, a2 = 0.f, a3 = 0.f;
    int b = g;
    for (; b + 3 * RG < nb; b += 4 * RG) {
        a0 += part[(size_t)b * SLOT + e];
        a1 += part[(size_t)(b + RG) * SLOT + e];
        a2 += part[(size_t)(b + 2 * RG) * SLOT + e];
        a3 += part[(size_t)(b + 3 * RG) * SLOT + e];
    }
    for (; b < nb; b += RG) a0 += part[(size_t)b * SLOT + e];
    part2[(size_t)g * SLOT + e] = (a0 + a1) + (a2 + a3);
}

// K1b stage 2: fold RG group-partials -> ws[0..4159] (gram 4096 | sums 64)
__global__ __launch_bounds__(256) void k1b2_reduce(const float* __restrict__ part2,
                                                   float* __restrict__ out) {
    const int e = blockIdx.x * 256 + threadIdx.x;
    if (e >= SLOT) return;
    float a0 = 0.f, a1 = 0.f, a2 = 0.f, a3 = 0.f;
    #pragma unroll
    for (int b = 0; b < RG; b += 4) {
        a0 += part2[(size_t)b * SLOT + e];
        a1 += part2[(size_t)(b + 1) * SLOT + e];
        a2 += part2[(size_t)(b + 2) * SLOT + e];
        a3 += part2[(size_t)(b + 3) * SLOT + e];
    }
    out[e] = (a0 + a1) + (a2 + a3);
}

// ---------------------------------------------------------------------------
// K2 helpers: 64x64 matmuls on one workgroup via MFMA. All operands are
// symmetric (polynomials in A), so B-frags read R's rows directly.
// ---------------------------------------------------------------------------
__device__ __forceinline__ bf16x8 ldfrag_h(const unsigned short* H, int rowbase, int k0, int l) {
    const int row = rowbase + (l & 15);
    const int koff = k0 + ((l >> 4) << 3);
    return *(const bf16x8*)&H[row * LDB + koff];
}
__device__ __forceinline__ bf16x8 ldfrag_lo(const float* F, bf16x8 hi, int rowbase, int k0, int l) {
    const int row = rowbase + (l & 15);
    const int koff = k0 + ((l >> 4) << 3);
    const float* p = F + row * 64 + koff;
    bf16x8 lo;
    #pragma unroll
    for (int j = 0; j < 8; ++j)
        lo[j] = (short)f2bf(p[j] - bf2f((unsigned short)hi[j]));
    return lo;
}

__device__ void mm_plain(const unsigned short* Lh, const unsigned short* Rh,
                         unsigned short* DH, float* DF, int tid) {
    const int w = tid >> 6, l = tid & 63;
    f32x4 acc[4];
    #pragma unroll
    for (int b = 0; b < 4; ++b) acc[b] = (f32x4){0.f, 0.f, 0.f, 0.f};
    #pragma unroll
    for (int k0 = 0; k0 < 64; k0 += 32) {
        const bf16x8 la = ldfrag_h(Lh, 16 * w, k0, l);
        #pragma unroll
        for (int b = 0; b < 4; ++b) {
            const bf16x8 rb = ldfrag_h(Rh, 16 * b, k0, l);
            acc[b] = __builtin_amdgcn_mfma_f32_16x16x32_bf16(la, rb, acc[b], 0, 0, 0);
        }
    }
    __syncthreads();  // allow in-place D==R
    #pragma unroll
    for (int b = 0; b < 4; ++b) {
        #pragma unroll
        for (int r = 0; r < 4; ++r) {
            const int row = 16 * w + ((l >> 4) << 2) + r;
            const int col = 16 * b + (l & 15);
            const float v = acc[b][r];
            if (DH) DH[row * LDB + col] = f2bf(v);
            if (DF) DF[row * 64 + col] = v;
        }
    }
    __syncthreads();
}

__device__ void mm_split(const unsigned short* Lh, const float* Lf,
                         const unsigned short* Rh, const float* Rf,
                         unsigned short* DH, float* DF, int tid) {
    const int w = tid >> 6, l = tid & 63;
    f32x4 acc[4];
    #pragma unroll
    for (int b = 0; b < 4; ++b) acc[b] = (f32x4){0.f, 0.f, 0.f, 0.f};
    #pragma unroll
    for (int k0 = 0; k0 < 64; k0 += 32) {
        const bf16x8 lah = ldfrag_h(Lh, 16 * w, k0, l);
        const bf16x8 lal = ldfrag_lo(Lf, lah, 16 * w, k0, l);
        #pragma unroll
        for (int b = 0; b < 4; ++b) {
            const bf16x8 rbh = ldfrag_h(Rh, 16 * b, k0, l);
            const bf16x8 rbl = ldfrag_lo(Rf, rbh, 16 * b, k0, l);
            acc[b] = __builtin_amdgcn_mfma_f32_16x16x32_bf16(lah, rbh, acc[b], 0, 0, 0);
            acc[b] = __builtin_amdgcn_mfma_f32_16x16x32_bf16(lah, rbl, acc[b], 0, 0, 0);
            acc[b] = __builtin_amdgcn_mfma_f32_16x16x32_bf16(lal, rbh, acc[b], 0, 0, 0);
        }
    }
    __syncthreads();  // allow in-place D==R
    #pragma unroll
    for (int b = 0; b < 4; ++b) {
        #pragma unroll
        for (int r = 0; r < 4; ++r) {
            const int row = 16 * w + ((l >> 4) << 2) + r;
            const int col = 16 * b + (l & 15);
            const float v = acc[b][r];
            if (DH) DH[row * LDB + col] = f2bf(v);
            if (DF) DF[row * 64 + col] = v;
        }
    }
    __syncthreads();
}

// ---------------------------------------------------------------------------
// K2: sigma -> Newton-Schulz inverse sqrt -> wm (as bf16 hi/lo pair), b.
// Single workgroup.
// ---------------------------------------------------------------------------
__global__ __launch_bounds__(256) void k2_ns(float* __restrict__ ws) {
    const float* gram = ws;
    const float* sums = ws + 4096;
    float* bvec = ws + 8256;
    float* Ag = ws + 8320;  // fp32 A = sigma/s (global, for polish lo-frags)
    unsigned short* wmh = (unsigned short*)(ws + 12416);  // bf16 hi of wm [64][64]
    unsigned short* wml = (unsigned short*)(ws + 14464);  // bf16 lo of wm [64][64]

    __shared__ float Zf[4096];
    __shared__ float Sf[4096];
    __shared__ __align__(16) unsigned short Ah[64 * LDB];
    __shared__ __align__(16) unsigned short ZhA[64 * LDB];
    __shared__ __align__(16) unsigned short Bh[64 * LDB];
    __shared__ float mu[64];
    __shared__ float sred[1];

    const int tid = threadIdx.x;
    const float invm = 1.0f / (float)MCOLS;

    if (tid < 64) mu[tid] = sums[tid] * invm;
    __syncthreads();

    // sigma -> Sf
    #pragma unroll
    for (int j = 0; j < 16; ++j) {
        const int e = tid * 16 + j;
        const int i = e >> 6, c = e & 63;
        Sf[e] = gram[e] * invm - mu[i] * mu[c] + ((i == c) ? 1e-3f : 0.0f);
    }
    __syncthreads();

    // s = ||sigma||_inf (Gershgorin bound on lambda_max)
    if (tid < 64) {
        float rs = 0.f;
        #pragma unroll
        for (int j = 0; j < 64; ++j) {
            const int c = (j + tid) & 63;  // rotate start -> conflict-free
            rs += fabsf(Sf[tid * 64 + c]);
        }
        #pragma unroll
        for (int m = 32; m > 0; m >>= 1) rs = fmaxf(rs, __shfl_xor(rs, m, 64));
        if (tid == 0) sred[0] = rs;
    }
    __syncthreads();
    const float s = sred[0];
    const float invs = 1.0f / s;

    // A = sigma/s (fp32 to Ag, bf16-hi to Ah); Z = I
    #pragma unroll
    for (int j = 0; j < 16; ++j) {
        const int e = tid * 16 + j;
        const int i = e >> 6, c = e & 63;
        const float a = Sf[e] * invs;
        Ag[e] = a;
        Ah[i * LDB + c] = f2bf(a);
        const float z = (i == c) ? 1.0f : 0.0f;
        Zf[e] = z;
        ZhA[i * LDB + c] = f2bf(z);
    }
    __syncthreads();

    // 4 plain bf16 NS iterations: Z <- 1.5 Z - 0.5 Z*(A*(Z*Z))
    for (int itn = 0; itn < 4; ++itn) {
        mm_plain(ZhA, ZhA, Bh, nullptr, tid);   // M = Z*Z
        mm_plain(Ah, Bh, Bh, nullptr, tid);     // W = A*M (in-place OK)
        mm_plain(ZhA, Bh, nullptr, Sf, tid);    // V = Z*W -> fp32
        #pragma unroll
        for (int j = 0; j < 16; ++j) {
            const int e = tid * 16 + j;
            const int i = e >> 6, c = e & 63;
            const float z = 1.5f * Zf[e] - 0.5f * Sf[e];
            Zf[e] = z;
            ZhA[i * LDB + c] = f2bf(z);
        }
        __syncthreads();
    }

    // polish: one NS step at ~fp32 precision via split-bf16 (hi*hi+hi*lo+lo*hi)
    mm_split(ZhA, Zf, ZhA, Zf, Bh, Sf, tid);     // M = Z*Z     -> (Bh, Sf)
    mm_split(Ah, Ag, Bh, Sf, Bh, Sf, tid);       // W = A*M     -> (Bh, Sf)
    mm_split(ZhA, Zf, Bh, Sf, nullptr, Sf, tid); // V = Z*W     -> Sf

    const float wsq = 1.0f / sqrtf(s);  // wm = Z / sqrt(s)
    #pragma unroll
    for (int j = 0; j < 16; ++j) {
        const int e = tid * 16 + j;
        const float z = 1.5f * Zf[e] - 0.5f * Sf[e];
        Zf[e] = z;
        const float wv = z * wsq;
        const unsigned short h = f2bf(wv);
        wmh[e] = h;
        wml[e] = f2bf(wv - bf2f(h));
    }
    __syncthreads();

    // b = wm * mu
    if (tid < 64) {
        float acc = 0.f;
        #pragma unroll
        for (int j = 0; j < 64; ++j) {
            const int c = (j + tid) & 63;
            acc += Zf[tid * 64 + c] * mu[c];
        }
        bvec[tid] = acc * wsq;
    }
}

// ---------------------------------------------------------------------------
// K3: out[n][c][hw] = sum_k wm[c][k] * X[n][k][hw] - bvec[c], via MFMA
// (split-bf16: hi*hi + hi*lo + lo*hi ~ fp32; lo*lo ~ 2^-16 dropped).
// R6 rewrite: R5's one-tile-per-block version was latency-bound (rocprof:
// 70us, hbm 2.2 TB/s = 27% peak, MfmaUtil 5%, VALUBusy 11% — per-block
// chain loadX->cvt->LDS->barrier->cold-wm-loads->MFMA->store, 6272 times,
// nothing in flight). Fix = k1's proven schedule: grid-stride (1024 blocks,
// ~6 tiles each) with register-prefetch of the next X tile across the
// MFMA+store section, and wm fragments + bvec hoisted to registers
// (block-invariant, 64 VGPR) so the per-tile path has no global latency.
// Layout unchanged from the verified R5 version: xT[pos][ch] bf16 hi/lo in
// LDS (stride 72 shorts); A-frag = positions, B-frag = wm rows; D[p][c]
// with p = 16w+(l>>4)*4+r -> contiguous f32x4 store per channel row
// (64 | 3136 so a tile never crosses an image).
// ---------------------------------------------------------------------------
__global__ __launch_bounds__(256) void k3_whiten(const float* __restrict__ X,
                                                 const float* __restrict__ ws,
                                                 float* __restrict__ out) {
    __shared__ __align__(16) unsigned short xh[64 * LDT];  // 9216 B
    __shared__ __align__(16) unsigned short xl[64 * LDT];  // 9216 B
    const int tid = threadIdx.x;
    const int w = tid >> 6, l = tid & 63;
    const int lm = l & 15;
    const int koffL = (l >> 4) << 3;

    const unsigned short* __restrict__ wmh = (const unsigned short*)(ws + 12416);
    const unsigned short* __restrict__ wml = (const unsigned short*)(ws + 14464);
    const float* __restrict__ bvec = ws + 8256;

    // hoist wm fragments + bias to registers: block-invariant (16 KB, L2-hot)
    bf16x8 fbh[2][4], fbl[2][4];
    #pragma unroll
    for (int kk = 0; kk < 2; ++kk) {
        #pragma unroll
        for (int cb = 0; cb < 4; ++cb) {
            const int c = cb * 16 + lm;
            fbh[kk][cb] = *(const bf16x8*)&wmh[c * 64 + kk * 32 + koffL];
            fbl[kk][cb] = *(const bf16x8*)&wml[c * 64 + kk * 32 + koffL];
        }
    }
    float bv[4];
    #pragma unroll
    for (int cb = 0; cb < 4; ++cb) bv[cb] = bvec[cb * 16 + lm];

    // prologue: load first tile (wave w covers channels w*16..w*16+15, pos l)
    float xv[16];
    uint32_t g = blockIdx.x;
    size_t base;
    {
        const uint32_t n = g / 49u;
        const uint32_t hw0 = (g - n * 49u) * 64u;
        base = (size_t)n * (CCH * HWSZ) + hw0;
        #pragma unroll
        for (int u = 0; u < 16; ++u)
            xv[u] = X[base + (size_t)(w * 16 + u) * HWSZ + l];
    }

    const int frow = (16 * w + lm) * LDT;
    const int p0 = 16 * w + ((l >> 4) << 2);

    for (;;) {
        __syncthreads();  // previous tile's LDS readers done
        // cvt + stage transposed: row l (position), cols w*16..w*16+15
        #pragma unroll
        for (int uu = 0; uu < 4; ++uu) {
            u16x4 hv, lv;
            #pragma unroll
            for (int j = 0; j < 4; ++j) {
                const float x = xv[uu * 4 + j];
                const unsigned short h = f2bf(x);
                hv[j] = h;
                lv[j] = f2bf(x - bf2f(h));
            }
            const int c0 = w * 16 + uu * 4;
            *(u16x4*)&xh[l * LDT + c0] = hv;
            *(u16x4*)&xl[l * LDT + c0] = lv;
        }
        __syncthreads();

        // prefetch next tile (loads overlap MFMA + store below)
        const uint32_t gn = g + K3NB;
        const bool more = gn < K3T;
        size_t basen = 0;
        if (more) {
            const uint32_t n = gn / 49u;
            const uint32_t hw0 = (gn - n * 49u) * 64u;
            basen = (size_t)n * (CCH * HWSZ) + hw0;
            #pragma unroll
            for (int u = 0; u < 16; ++u)
                xv[u] = X[basen + (size_t)(w * 16 + u) * HWSZ + l];
        }

        f32x4 acc[4];
        #pragma unroll
        for (int b = 0; b < 4; ++b) acc[b] = (f32x4){0.f, 0.f, 0.f, 0.f};
        #pragma unroll
        for (int kk = 0; kk < 2; ++kk) {
            const bf16x8 fah = *(const bf16x8*)&xh[frow + kk * 32 + koffL];
            const bf16x8 fal = *(const bf16x8*)&xl[frow + kk * 32 + koffL];
            #pragma unroll
            for (int cb = 0; cb < 4; ++cb) {
                acc[cb] = __builtin_amdgcn_mfma_f32_16x16x32_bf16(fah, fbh[kk][cb], acc[cb], 0, 0, 0);
                acc[cb] = __builtin_amdgcn_mfma_f32_16x16x32_bf16(fah, fbl[kk][cb], acc[cb], 0, 0, 0);
                acc[cb] = __builtin_amdgcn_mfma_f32_16x16x32_bf16(fal, fbh[kk][cb], acc[cb], 0, 0, 0);
            }
        }

        // store: lane's 4 acc values = 4 consecutive positions of channel c
        #pragma unroll
        for (int cb = 0; cb < 4; ++cb) {
            const int c = cb * 16 + lm;
            f32x4 v;
            v[0] = acc[cb][0] - bv[cb];
            v[1] = acc[cb][1] - bv[cb];
            v[2] = acc[cb][2] - bv[cb];
            v[3] = acc[cb][3] - bv[cb];
            *(f32x4*)&out[base + (size_t)c * HWSZ + p0] = v;
        }

        if (!more) break;
        g = gn;
        base = basen;
    }
}

// ---------------------------------------------------------------------------
extern "C" void kernel_launch(void* const* d_in, const int* in_sizes, int n_in,
                              void* d_out, int out_size, void* d_ws, size_t ws_size,
                              hipStream_t stream) {
    (void)in_sizes; (void)n_in; (void)out_size;
    const float* X = (const float*)d_in[0];
    float* out = (float*)d_out;
    float* ws = (float*)d_ws;

    // ws layout: [0..WS_TAIL) result area | nb K1 slots | RG stage-2 slots
    long avail = (long)(ws_size / sizeof(float)) - WS_TAIL - (long)RG * SLOT;
    int nb = (int)(avail / SLOT);
    if (nb > K1MAX) nb = K1MAX;
    if (nb < 1) nb = 1;

    float* part = ws + WS_TAIL;
    float* part2 = part + (size_t)nb * SLOT;

    k1_gram<<<nb, 256, 0, stream>>>(X, part, nb);
    k1b1_reduce<<<17 * RG, 256, 0, stream>>>(part, part2, nb);
    k1b2_reduce<<<17, 256, 0, stream>>>(part2, ws);
    k2_ns<<<1, 256, 0, stream>>>(ws);
    k3_whiten<<<K3NB, 256, 0, stream>>>(X, ws, out);
}

// Round 4
// 242.285 us; speedup vs baseline: 1.1125x; 1.0022x over previous
//
#include <hip/hip_runtime.h>
#include <stdint.h>

// Problem constants
#define CCH   64
#define HWSZ  3136        // 56*56
#define NB    128
#define MCOLS 401408      // NB*HWSZ
#define TK    128         // K1 tile columns
#define NTILES 3136       // MCOLS / TK
#define LDK   136         // TK+8 bf16 stride (272 B, 16B-aligned, conflict-benign)
#define LDB   72          // K2 bf16 row stride (144 B, 16B-aligned)
#define SLOT  4160        // per-block partial: 4096 gram + 64 sums (floats)
#define WS_TAIL 16512     // gram|sums|wm|bvec|Ag|wmh|wml floats at ws[0..)
#define RG    16          // reduction tree fan-in groups (512 slots -> 16)
#define K1MAX 512         // k1 grid: 2 blocks/CU, ~6 tiles/block (halves partials vs 1024)
#define LDT   72          // K3 xT row stride in shorts (144 B, 16B-aligned)
#define K3NB  1024        // K3 grid: 4 blocks/CU, ~6 tiles/block
#define K3T   6272        // MCOLS/64 posgroups

typedef short bf16x8 __attribute__((ext_vector_type(8)));
typedef float f32x4  __attribute__((ext_vector_type(4)));
typedef unsigned short u16x4 __attribute__((ext_vector_type(4)));

__device__ __forceinline__ unsigned short f2bf(float f) {
    union { float f; uint32_t u; } v; v.f = f;
    uint32_t r = v.u + 0x7fffu + ((v.u >> 16) & 1u);   // round-to-nearest-even
    return (unsigned short)(r >> 16);
}
__device__ __forceinline__ float bf2f(unsigned short h) {
    union { uint32_t u; float f; } v; v.u = ((uint32_t)h) << 16; return v.f;
}
__device__ __forceinline__ uint32_t fbits(float f) {
    union { float f; uint32_t u; } v; v.f = f; return v.u;
}
__device__ __forceinline__ float bcast(uint32_t u) {
    union { uint32_t u; float f; } v; v.u = u; return v.f;
}

// ---------------------------------------------------------------------------
// K1: per-channel sums + gram = X*X^T via bf16 MFMA (gram symmetric => immune
// to C/D transpose). Grid-stride over tiles, private per-block partials (no
// atomics — R1: 6.4M RMWs on 16KB serialized to 700us). Register-prefetch
// pipeline (next tile's loads issued before the MFMA section).
// ---------------------------------------------------------------------------
__global__ __launch_bounds__(256) void k1_gram(const float* __restrict__ X,
                                               float* __restrict__ part,
                                               int nb) {
    __shared__ __align__(16) unsigned short tile[CCH * LDK];  // 17408 B
    const int tid = threadIdx.x;
    const int w = tid >> 6, l = tid & 63;

    f32x4 acc[4];
    #pragma unroll
    for (int b = 0; b < 4; ++b) acc[b] = (f32x4){0.f, 0.f, 0.f, 0.f};
    float sacc[16];
    #pragma unroll
    for (int i = 0; i < 16; ++i) sacc[i] = 0.f;

    float2 xv[16];

    // prologue: load first tile into registers
    uint32_t t = blockIdx.x;
    {
        const uint32_t s = t * TK + 2u * (uint32_t)l;  // even => float2 never crosses n
        const uint32_t n = s / HWSZ;
        const uint32_t hw = s - n * HWSZ;
        const size_t base = (size_t)n * (CCH * HWSZ) + hw + (size_t)w * HWSZ;
        #pragma unroll
        for (int i = 0; i < 16; ++i)
            xv[i] = *(const float2*)(X + base + (size_t)i * (4u * HWSZ));
    }

    for (;;) {
        __syncthreads();  // previous tile's LDS readers done
        // stage registers -> LDS (channel c = 4*i + w)
        #pragma unroll
        for (int i = 0; i < 16; ++i) {
            sacc[i] += xv[i].x + xv[i].y;
            const int c = 4 * i + w;
            *(uint32_t*)&tile[c * LDK + 2 * l] =
                (uint32_t)f2bf(xv[i].x) | ((uint32_t)f2bf(xv[i].y) << 16);
        }
        __syncthreads();

        // prefetch next tile (loads overlap the MFMA section below)
        const uint32_t tn = t + (uint32_t)nb;
        const bool more = tn < NTILES;
        if (more) {
            const uint32_t s = tn * TK + 2u * (uint32_t)l;
            const uint32_t n = s / HWSZ;
            const uint32_t hw = s - n * HWSZ;
            const size_t base = (size_t)n * (CCH * HWSZ) + hw + (size_t)w * HWSZ;
            #pragma unroll
            for (int i = 0; i < 16; ++i)
                xv[i] = *(const float2*)(X + base + (size_t)i * (4u * HWSZ));
        }

        // MFMA: wave w computes gram row-block w x col-blocks 0..3
        #pragma unroll
        for (int k0 = 0; k0 < TK; k0 += 32) {
            const int koff = k0 + ((l >> 4) << 3);
            const bf16x8 fa = *(const bf16x8*)&tile[(16 * w + (l & 15)) * LDK + koff];
            #pragma unroll
            for (int bj = 0; bj < 4; ++bj) {
                const bf16x8 fb = *(const bf16x8*)&tile[(16 * bj + (l & 15)) * LDK + koff];
                acc[bj] = __builtin_amdgcn_mfma_f32_16x16x32_bf16(fa, fb, acc[bj], 0, 0, 0);
            }
        }

        if (!more) break;
        t = tn;
    }

    // epilogue: plain stores to this block's private slot
    float* pg = part + (size_t)blockIdx.x * SLOT;
    #pragma unroll
    for (int bj = 0; bj < 4; ++bj) {
        #pragma unroll
        for (int r = 0; r < 4; ++r) {
            const int row = 16 * w + ((l >> 4) << 2) + r;
            const int col = 16 * bj + (l & 15);
            pg[row * 64 + col] = acc[bj][r];
        }
    }
    #pragma unroll
    for (int i = 0; i < 16; ++i) {
        float v = sacc[i];
        #pragma unroll
        for (int m = 32; m > 0; m >>= 1) v += __shfl_xor(v, m, 64);
        if (l == 0) pg[4096 + 4 * i + w] = v;
    }
}

// ---------------------------------------------------------------------------
// K1b: 17*RG blocks. Block (g = bx/17) sums slots {g, g+RG, ...} into
// part2[g]. 4 independent accumulators break the dependent-load chain.
// Groups with no slots (nb < RG) write zeros — k2's fold stays correct.
// ---------------------------------------------------------------------------
__global__ __launch_bounds__(256) void k1b1_reduce(const float* __restrict__ part,
                                                   float* __restrict__ part2,
                                                   int nb) {
    const int bx = blockIdx.x;
    const int g = bx / 17;
    const int e = (bx - g * 17) * 256 + threadIdx.x;
    if (e >= SLOT) return;
    float a0 = 0.f, a1 = 0.f, a2 = 0.f, a3 = 0.f;
    int b = g;
    for (; b + 3 * RG < nb; b += 4 * RG) {
        a0 += part[(size_t)b * SLOT + e];
        a1 += part[(size_t)(b + RG) * SLOT + e];
        a2 += part[(size_t)(b + 2 * RG) * SLOT + e];
        a3 += part[(size_t)(b + 3 * RG) * SLOT + e];
    }
    for (; b < nb; b += RG) a0 += part[(size_t)b * SLOT + e];
    part2[(size_t)g * SLOT + e] = (a0 + a1) + (a2 + a3);
}

// ---------------------------------------------------------------------------
// K2 helpers: 64x64 matmuls on one workgroup via MFMA. All operands are
// symmetric (polynomials in A), so B-frags read R's rows directly.
// ---------------------------------------------------------------------------
__device__ __forceinline__ bf16x8 ldfrag_h(const unsigned short* H, int rowbase, int k0, int l) {
    const int row = rowbase + (l & 15);
    const int koff = k0 + ((l >> 4) << 3);
    return *(const bf16x8*)&H[row * LDB + koff];
}
__device__ __forceinline__ bf16x8 ldfrag_lo(const float* F, bf16x8 hi, int rowbase, int k0, int l) {
    const int row = rowbase + (l & 15);
    const int koff = k0 + ((l >> 4) << 3);
    const float* p = F + row * 64 + koff;
    bf16x8 lo;
    #pragma unroll
    for (int j = 0; j < 8; ++j)
        lo[j] = (short)f2bf(p[j] - bf2f((unsigned short)hi[j]));
    return lo;
}

__device__ void mm_plain(const unsigned short* Lh, const unsigned short* Rh,
                         unsigned short* DH, float* DF, int tid) {
    const int w = tid >> 6, l = tid & 63;
    f32x4 acc[4];
    #pragma unroll
    for (int b = 0; b < 4; ++b) acc[b] = (f32x4){0.f, 0.f, 0.f, 0.f};
    #pragma unroll
    for (int k0 = 0; k0 < 64; k0 += 32) {
        const bf16x8 la = ldfrag_h(Lh, 16 * w, k0, l);
        #pragma unroll
        for (int b = 0; b < 4; ++b) {
            const bf16x8 rb = ldfrag_h(Rh, 16 * b, k0, l);
            acc[b] = __builtin_amdgcn_mfma_f32_16x16x32_bf16(la, rb, acc[b], 0, 0, 0);
        }
    }
    __syncthreads();  // allow in-place D==R
    #pragma unroll
    for (int b = 0; b < 4; ++b) {
        #pragma unroll
        for (int r = 0; r < 4; ++r) {
            const int row = 16 * w + ((l >> 4) << 2) + r;
            const int col = 16 * b + (l & 15);
            const float v = acc[b][r];
            if (DH) DH[row * LDB + col] = f2bf(v);
            if (DF) DF[row * 64 + col] = v;
        }
    }
    __syncthreads();
}

__device__ void mm_split(const unsigned short* Lh, const float* Lf,
                         const unsigned short* Rh, const float* Rf,
                         unsigned short* DH, float* DF, int tid) {
    const int w = tid >> 6, l = tid & 63;
    f32x4 acc[4];
    #pragma unroll
    for (int b = 0; b < 4; ++b) acc[b] = (f32x4){0.f, 0.f, 0.f, 0.f};
    #pragma unroll
    for (int k0 = 0; k0 < 64; k0 += 32) {
        const bf16x8 lah = ldfrag_h(Lh, 16 * w, k0, l);
        const bf16x8 lal = ldfrag_lo(Lf, lah, 16 * w, k0, l);
        #pragma unroll
        for (int b = 0; b < 4; ++b) {
            const bf16x8 rbh = ldfrag_h(Rh, 16 * b, k0, l);
            const bf16x8 rbl = ldfrag_lo(Rf, rbh, 16 * b, k0, l);
            acc[b] = __builtin_amdgcn_mfma_f32_16x16x32_bf16(lah, rbh, acc[b], 0, 0, 0);
            acc[b] = __builtin_amdgcn_mfma_f32_16x16x32_bf16(lah, rbl, acc[b], 0, 0, 0);
            acc[b] = __builtin_amdgcn_mfma_f32_16x16x32_bf16(lal, rbh, acc[b], 0, 0, 0);
        }
    }
    __syncthreads();  // allow in-place D==R
    #pragma unroll
    for (int b = 0; b < 4; ++b) {
        #pragma unroll
        for (int r = 0; r < 4; ++r) {
            const int row = 16 * w + ((l >> 4) << 2) + r;
            const int col = 16 * b + (l & 15);
            const float v = acc[b][r];
            if (DH) DH[row * LDB + col] = f2bf(v);
            if (DF) DF[row * 64 + col] = v;
        }
    }
    __syncthreads();
}

// ---------------------------------------------------------------------------
// K2: fold 16 group-partials (266 KB, L2-hot — replaces the old k1b2 launch)
// -> sigma -> Newton-Schulz inverse sqrt -> wm (bf16 hi/lo), b. Single block.
// ---------------------------------------------------------------------------
__global__ __launch_bounds__(256) void k2_ns(const float* __restrict__ part2,
                                             float* __restrict__ ws) {
    float* bvec = ws + 8256;
    float* Ag = ws + 8320;  // fp32 A = sigma/s (global, for polish lo-frags)
    unsigned short* wmh = (unsigned short*)(ws + 12416);  // bf16 hi of wm [64][64]
    unsigned short* wml = (unsigned short*)(ws + 14464);  // bf16 lo of wm [64][64]

    __shared__ float Zf[4096];
    __shared__ float Sf[4096];
    __shared__ __align__(16) unsigned short Ah[64 * LDB];
    __shared__ __align__(16) unsigned short ZhA[64 * LDB];
    __shared__ __align__(16) unsigned short Bh[64 * LDB];
    __shared__ float mu[64];
    __shared__ float sred[1];

    const int tid = threadIdx.x;
    const float invm = 1.0f / (float)MCOLS;

    // fold channel sums -> mu
    if (tid < 64) {
        float a = 0.f;
        #pragma unroll
        for (int b = 0; b < RG; ++b) a += part2[(size_t)b * SLOT + 4096 + tid];
        mu[tid] = a * invm;
    }
    __syncthreads();

    // fold gram -> sigma -> Sf (per-thread 16 contiguous elems, 4-acc ILP)
    #pragma unroll
    for (int j = 0; j < 16; ++j) {
        const int e = tid * 16 + j;
        const int i = e >> 6, c = e & 63;
        float a0 = 0.f, a1 = 0.f, a2 = 0.f, a3 = 0.f;
        #pragma unroll
        for (int b = 0; b < RG; b += 4) {
            a0 += part2[(size_t)(b + 0) * SLOT + e];
            a1 += part2[(size_t)(b + 1) * SLOT + e];
            a2 += part2[(size_t)(b + 2) * SLOT + e];
            a3 += part2[(size_t)(b + 3) * SLOT + e];
        }
        const float g = (a0 + a1) + (a2 + a3);
        Sf[e] = g * invm - mu[i] * mu[c] + ((i == c) ? 1e-3f : 0.0f);
    }
    __syncthreads();

    // s = ||sigma||_inf (Gershgorin bound on lambda_max)
    if (tid < 64) {
        float rs = 0.f;
        #pragma unroll
        for (int j = 0; j < 64; ++j) {
            const int c = (j + tid) & 63;  // rotate start -> conflict-free
            rs += fabsf(Sf[tid * 64 + c]);
        }
        #pragma unroll
        for (int m = 32; m > 0; m >>= 1) rs = fmaxf(rs, __shfl_xor(rs, m, 64));
        if (tid == 0) sred[0] = rs;
    }
    __syncthreads();
    const float s = sred[0];
    const float invs = 1.0f / s;

    // A = sigma/s (fp32 to Ag, bf16-hi to Ah); Z = I
    #pragma unroll
    for (int j = 0; j < 16; ++j) {
        const int e = tid * 16 + j;
        const int i = e >> 6, c = e & 63;
        const float a = Sf[e] * invs;
        Ag[e] = a;
        Ah[i * LDB + c] = f2bf(a);
        const float z = (i == c) ? 1.0f : 0.0f;
        Zf[e] = z;
        ZhA[i * LDB + c] = f2bf(z);
    }
    __syncthreads();

    // 4 plain bf16 NS iterations: Z <- 1.5 Z - 0.5 Z*(A*(Z*Z))
    for (int itn = 0; itn < 4; ++itn) {
        mm_plain(ZhA, ZhA, Bh, nullptr, tid);   // M = Z*Z
        mm_plain(Ah, Bh, Bh, nullptr, tid);     // W = A*M (in-place OK)
        mm_plain(ZhA, Bh, nullptr, Sf, tid);    // V = Z*W -> fp32
        #pragma unroll
        for (int j = 0; j < 16; ++j) {
            const int e = tid * 16 + j;
            const int i = e >> 6, c = e & 63;
            const float z = 1.5f * Zf[e] - 0.5f * Sf[e];
            Zf[e] = z;
            ZhA[i * LDB + c] = f2bf(z);
        }
        __syncthreads();
    }

    // polish: one NS step at ~fp32 precision via split-bf16 (hi*hi+hi*lo+lo*hi)
    mm_split(ZhA, Zf, ZhA, Zf, Bh, Sf, tid);     // M = Z*Z     -> (Bh, Sf)
    mm_split(Ah, Ag, Bh, Sf, Bh, Sf, tid);       // W = A*M     -> (Bh, Sf)
    mm_split(ZhA, Zf, Bh, Sf, nullptr, Sf, tid); // V = Z*W     -> Sf

    const float wsq = 1.0f / sqrtf(s);  // wm = Z / sqrt(s)
    #pragma unroll
    for (int j = 0; j < 16; ++j) {
        const int e = tid * 16 + j;
        const float z = 1.5f * Zf[e] - 0.5f * Sf[e];
        Zf[e] = z;
        const float wv = z * wsq;
        const unsigned short h = f2bf(wv);
        wmh[e] = h;
        wml[e] = f2bf(wv - bf2f(h));
    }
    __syncthreads();

    // b = wm * mu
    if (tid < 64) {
        float acc = 0.f;
        #pragma unroll
        for (int j = 0; j < 64; ++j) {
            const int c = (j + tid) & 63;
            acc += Zf[tid * 64 + c] * mu[c];
        }
        bvec[tid] = acc * wsq;
    }
}

// ---------------------------------------------------------------------------
// K3: out[n][c][hw] = sum_k wm[c][k] * X[n][k][hw] - bvec[c], via MFMA
// (split-bf16: hi*hi + hi*lo + lo*hi ~ fp32; lo*lo ~ 2^-16 dropped).
// R6: grid-stride + register-prefetch + wm frags hoisted (fixed R5's
// latency-bound one-tile-per-block schedule: 70us -> ~43us).
// R8: hi/lo split via v_perm_b32 truncation packs (3 VALU/elem vs ~10):
// hi = trunc16(x) (1 perm packs 2 elems), r = x - hi exact, lo = trunc16(r)
// (1 perm). |x - (hi+lo)| <= 2^-16|x| — negligible vs bf16 gram error.
// ---------------------------------------------------------------------------
__global__ __launch_bounds__(256) void k3_whiten(const float* __restrict__ X,
                                                 const float* __restrict__ ws,
                                                 float* __restrict__ out) {
    __shared__ __align__(16) unsigned short xh[64 * LDT];  // 9216 B
    __shared__ __align__(16) unsigned short xl[64 * LDT];  // 9216 B
    const int tid = threadIdx.x;
    const int w = tid >> 6, l = tid & 63;
    const int lm = l & 15;
    const int koffL = (l >> 4) << 3;

    const unsigned short* __restrict__ wmh = (const unsigned short*)(ws + 12416);
    const unsigned short* __restrict__ wml = (const unsigned short*)(ws + 14464);
    const float* __restrict__ bvec = ws + 8256;

    // hoist wm fragments + bias to registers: block-invariant (16 KB, L2-hot)
    bf16x8 fbh[2][4], fbl[2][4];
    #pragma unroll
    for (int kk = 0; kk < 2; ++kk) {
        #pragma unroll
        for (int cb = 0; cb < 4; ++cb) {
            const int c = cb * 16 + lm;
            fbh[kk][cb] = *(const bf16x8*)&wmh[c * 64 + kk * 32 + koffL];
            fbl[kk][cb] = *(const bf16x8*)&wml[c * 64 + kk * 32 + koffL];
        }
    }
    float bv[4];
    #pragma unroll
    for (int cb = 0; cb < 4; ++cb) bv[cb] = bvec[cb * 16 + lm];

    // prologue: load first tile (wave w covers channels w*16..w*16+15, pos l)
    float xv[16];
    uint32_t g = blockIdx.x;
    size_t base;
    {
        const uint32_t n = g / 49u;
        const uint32_t hw0 = (g - n * 49u) * 64u;
        base = (size_t)n * (CCH * HWSZ) + hw0;
        #pragma unroll
        for (int u = 0; u < 16; ++u)
            xv[u] = X[base + (size_t)(w * 16 + u) * HWSZ + l];
    }

    const int frow = (16 * w + lm) * LDT;
    const int p0 = 16 * w + ((l >> 4) << 2);

    for (;;) {
        __syncthreads();  // previous tile's LDS readers done
        // trunc-split + stage transposed: row l (position), cols w*16..w*16+15
        #pragma unroll
        for (int uu = 0; uu < 4; ++uu) {
            const int j0 = uu * 4;
            const uint32_t a0 = fbits(xv[j0 + 0]);
            const uint32_t a1 = fbits(xv[j0 + 1]);
            const uint32_t a2 = fbits(xv[j0 + 2]);
            const uint32_t a3 = fbits(xv[j0 + 3]);
            uint2 hv, lv;
            hv.x = __builtin_amdgcn_perm(a1, a0, 0x07060302u);  // [hi16(x0), hi16(x1)]
            hv.y = __builtin_amdgcn_perm(a3, a2, 0x07060302u);
            const float r0 = xv[j0 + 0] - bcast(a0 & 0xFFFF0000u);  // exact
            const float r1 = xv[j0 + 1] - bcast(a1 & 0xFFFF0000u);
            const float r2 = xv[j0 + 2] - bcast(a2 & 0xFFFF0000u);
            const float r3 = xv[j0 + 3] - bcast(a3 & 0xFFFF0000u);
            lv.x = __builtin_amdgcn_perm(fbits(r1), fbits(r0), 0x07060302u);
            lv.y = __builtin_amdgcn_perm(fbits(r3), fbits(r2), 0x07060302u);
            const int c0 = w * 16 + uu * 4;
            *(uint2*)&xh[l * LDT + c0] = hv;
            *(uint2*)&xl[l * LDT + c0] = lv;
        }
        __syncthreads();

        // prefetch next tile (loads overlap MFMA + store below)
        const uint32_t gn = g + K3NB;
        const bool more = gn < K3T;
        size_t basen = 0;
        if (more) {
            const uint32_t n = gn / 49u;
            const uint32_t hw0 = (gn - n * 49u) * 64u;
            basen = (size_t)n * (CCH * HWSZ) + hw0;
            #pragma unroll
            for (int u = 0; u < 16; ++u)
                xv[u] = X[basen + (size_t)(w * 16 + u) * HWSZ + l];
        }

        f32x4 acc[4];
        #pragma unroll
        for (int b = 0; b < 4; ++b) acc[b] = (f32x4){0.f, 0.f, 0.f, 0.f};
        #pragma unroll
        for (int kk = 0; kk < 2; ++kk) {
            const bf16x8 fah = *(const bf16x8*)&xh[frow + kk * 32 + koffL];
            const bf16x8 fal = *(const bf16x8*)&xl[frow + kk * 32 + koffL];
            #pragma unroll
            for (int cb = 0; cb < 4; ++cb) {
                acc[cb] = __builtin_amdgcn_mfma_f32_16x16x32_bf16(fah, fbh[kk][cb], acc[cb], 0, 0, 0);
                acc[cb] = __builtin_amdgcn_mfma_f32_16x16x32_bf16(fah, fbl[kk][cb], acc[cb], 0, 0, 0);
                acc[cb] = __builtin_amdgcn_mfma_f32_16x16x32_bf16(fal, fbh[kk][cb], acc[cb], 0, 0, 0);
            }
        }

        // store: lane's 4 acc values = 4 consecutive positions of channel c
        #pragma unroll
        for (int cb = 0; cb < 4; ++cb) {
            const int c = cb * 16 + lm;
            f32x4 v;
            v[0] = acc[cb][0] - bv[cb];
            v[1] = acc[cb][1] - bv[cb];
            v[2] = acc[cb][2] - bv[cb];
            v[3] = acc[cb][3] - bv[cb];
            *(f32x4*)&out[base + (size_t)c * HWSZ + p0] = v;
        }

        if (!more) break;
        g = gn;
        base = basen;
    }
}

// ---------------------------------------------------------------------------
extern "C" void kernel_launch(void* const* d_in, const int* in_sizes, int n_in,
                              void* d_out, int out_size, void* d_ws, size_t ws_size,
                              hipStream_t stream) {
    (void)in_sizes; (void)n_in; (void)out_size;
    const float* X = (const float*)d_in[0];
    float* out = (float*)d_out;
    float* ws = (float*)d_ws;

    // ws layout: [0..WS_TAIL) result area | nb K1 slots | RG group slots
    long avail = (long)(ws_size / sizeof(float)) - WS_TAIL - (long)RG * SLOT;
    int nb = (int)(avail / SLOT);
    if (nb > K1MAX) nb = K1MAX;
    if (nb < 1) nb = 1;

    float* part = ws + WS_TAIL;
    float* part2 = part + (size_t)nb * SLOT;

    k1_gram<<<nb, 256, 0, stream>>>(X, part, nb);
    k1b1_reduce<<<17 * RG, 256, 0, stream>>>(part, part2, nb);
    k2_ns<<<1, 256, 0, stream>>>(part2, ws);
    k3_whiten<<<K3NB, 256, 0, stream>>>(X, ws, out);
}